// Round 7
// baseline (131.419 us; speedup 1.0000x reference)
//
#include <hip/hip_runtime.h>
#include <stdint.h>

#define SEQ 4096
#define DMODEL 768
#define NHEADS 12
#define DKH 64

typedef __attribute__((ext_vector_type(8))) short short8;
typedef __attribute__((ext_vector_type(4))) float floatx4;
typedef __attribute__((ext_vector_type(16))) float floatx16;

__device__ __forceinline__ unsigned short f2bf(float f) {
    unsigned int u = __float_as_uint(f);
    u += 0x7fffu + ((u >> 16) & 1u);          // round-to-nearest-even
    return (unsigned short)(u >> 16);
}

__device__ __forceinline__ float exp2fast(float x) {
    return __builtin_amdgcn_exp2f(x);
}

__device__ __forceinline__ unsigned int cvt_pk_bf16(float lo, float hi) {
    unsigned int r;
    asm("v_cvt_pk_bf16_f32 %0, %1, %2" : "=v"(r) : "v"(lo), "v"(hi));
    return r;
}

// XOR swizzle: spread a row-strided access across 8 16-byte slots.
__device__ __forceinline__ int swz(int row, int colb) {
    return colb ^ ((row & 7) << 4);
}

// async global->LDS, 16 bytes per lane. LDS dest wave-uniform base + lane*16.
__device__ __forceinline__ void async_copy16(void* lds, const void* g) {
    __builtin_amdgcn_global_load_lds(
        (const __attribute__((address_space(1))) void*)g,
        (__attribute__((address_space(3))) void*)lds,
        16, 0, 0);
}

// ---------------------------------------------------------------- casts
__global__ __launch_bounds__(256) void castk(const float* __restrict__ src,
                                             unsigned short* __restrict__ dst,
                                             int n4) {
    int i = blockIdx.x * 256 + threadIdx.x;
    if (i >= n4) return;
    float4 v = ((const float4*)src)[i];
    ushort4 o;
    o.x = f2bf(v.x); o.y = f2bf(v.y); o.z = f2bf(v.z); o.w = f2bf(v.w);
    ((ushort4*)dst)[i] = o;
}

// all four 768x768 weights in one launch; dst regions contiguous
__global__ __launch_bounds__(256) void castw(const float* __restrict__ w0,
                                             const float* __restrict__ w1,
                                             const float* __restrict__ w2,
                                             const float* __restrict__ w3,
                                             unsigned short* __restrict__ dst) {
    int b = blockIdx.x;              // 2304 = 4 * 576
    int wsel = b / 576;
    int i = (b % 576) * 256 + threadIdx.x;   // < 147456 float4 groups
    const float* src = (wsel == 0) ? w0 : (wsel == 1) ? w1 : (wsel == 2) ? w2 : w3;
    float4 v = ((const float4*)src)[i];
    ushort4 o;
    o.x = f2bf(v.x); o.y = f2bf(v.y); o.z = f2bf(v.z); o.w = f2bf(v.w);
    ((ushort4*)(dst + (size_t)wsel * 589824))[i] = o;
}

// stage one 128x64 A-tile + 64x64 B-tile into LDS buffer (6 loads/wave, 256 thr)
#define STAGE_G(bsel, kb)                                                              \
    do {                                                                               \
        char* As_ = smem + (bsel) * 24576;                                             \
        _Pragma("unroll") for (int ii = 0; ii < 4; ii++) {                             \
            int o = ii * 4096 + t * 16;                                                \
            int row = o >> 7, colb = o & 127;                                          \
            async_copy16(As_ + ii * 4096 + wid * 1024,                                 \
                         (const char*)A + ((size_t)(rowBase + row) * DMODEL + (kb)) * 2 \
                             + swz(row, colb));                                        \
        }                                                                              \
        _Pragma("unroll") for (int ii = 0; ii < 2; ii++) {                             \
            int o = ii * 4096 + t * 16;                                                \
            int row = o >> 7, colb = o & 127;                                          \
            async_copy16(As_ + 16384 + ii * 4096 + wid * 1024,                         \
                         (const char*)B + ((size_t)(colBase + row) * DMODEL + (kb)) * 2 \
                             + swz(row, colb));                                        \
        }                                                                              \
    } while (0)

// shared inner compute for the 128x64 GEMM tile (16 MFMA per wave)
#define GEMM_COMPUTE(As, Bs)                                                           \
    do {                                                                               \
        short8 a_[4][2], b_[2][2];                                                     \
        _Pragma("unroll") for (int m = 0; m < 4; m++)                                  \
            _Pragma("unroll") for (int kk = 0; kk < 2; kk++) {                         \
                int row = wr * 64 + m * 16 + lr;                                       \
                int colb = kk * 64 + lg * 16;                                          \
                a_[m][kk] = *(const short8*)((As) + row * 128 + swz(row, colb));       \
            }                                                                          \
        _Pragma("unroll") for (int n = 0; n < 2; n++)                                  \
            _Pragma("unroll") for (int kk = 0; kk < 2; kk++) {                         \
                int row = wc * 32 + n * 16 + lr;                                       \
                int colb = kk * 64 + lg * 16;                                          \
                b_[n][kk] = *(const short8*)((Bs) + row * 128 + swz(row, colb));       \
            }                                                                          \
        _Pragma("unroll") for (int m = 0; m < 4; m++)                                  \
            _Pragma("unroll") for (int n = 0; n < 2; n++)                              \
                _Pragma("unroll") for (int kk = 0; kk < 2; kk++)                       \
                    acc[m][n] = __builtin_amdgcn_mfma_f32_16x16x32_bf16(               \
                        a_[m][kk], b_[n][kk], acc[m][n], 0, 0, 0);                     \
    } while (0)

// ---------------------------------------------------------------- fused QKV GEMM
// A [4096][768] bf16; W = wq|wk|wv contiguous ([out][in] each).
// grid (32, 36): by/12 = proj (0:Q scaled, 1:K, 2:V^T), by%12 = col tile.
// Out: Qb | Kb ([H][SEQ][64]) | VTb ([768][SEQ], bit2<->bit3 key permute).
__global__ __launch_bounds__(256, 2)
void gemm_qkv(const unsigned short* __restrict__ A,
              const unsigned short* __restrict__ W,
              unsigned short* __restrict__ OutBase, float qscale) {
    __shared__ __align__(128) char smem[49152];  // 2 x (A 16K | B 8K)

    const int t = threadIdx.x;
    const int wid = t >> 6, lane = t & 63;
    const int lr = lane & 15, lg = lane >> 4;
    const int wr = wid >> 1, wc = wid & 1;
    const int rowBase = blockIdx.x * 128;
    const int proj = blockIdx.y / 12;
    const int colBase = (blockIdx.y % 12) * 64;
    const unsigned short* B = W + (size_t)proj * 589824;

    const floatx4 zero4 = {0.f, 0.f, 0.f, 0.f};
    floatx4 acc[4][2];
#pragma unroll
    for (int m = 0; m < 4; m++)
#pragma unroll
        for (int n = 0; n < 2; n++) acc[m][n] = zero4;

    STAGE_G(0, 0);
    for (int i = 0; i < 12; ++i) {
        __builtin_amdgcn_s_barrier();              // all waves done reading buf[(i+1)&1]
        __builtin_amdgcn_sched_barrier(0);
        if (i < 11) {
            STAGE_G((i + 1) & 1, (i + 1) * 64);
            asm volatile("s_waitcnt vmcnt(6)" ::: "memory");  // own stage(i) done
        } else {
            asm volatile("s_waitcnt vmcnt(0)" ::: "memory");
        }
        __builtin_amdgcn_s_barrier();              // everyone's stage(i) done
        __builtin_amdgcn_sched_barrier(0);
        char* As = smem + (i & 1) * 24576;
        GEMM_COMPUTE(As, As + 16384);
    }

    if (proj < 2) {
        unsigned short* O = OutBase + (size_t)proj * 3145728;
        float scale = (proj == 0) ? qscale : 1.0f;
#pragma unroll
        for (int m = 0; m < 4; m++)
#pragma unroll
            for (int n = 0; n < 2; n++)
#pragma unroll
                for (int r = 0; r < 4; r++) {
                    int srow = rowBase + wr * 64 + m * 16 + lg * 4 + r;
                    int col = colBase + wc * 32 + n * 16 + lr;
                    int h = col >> 6, d = col & 63;
                    O[((size_t)h * SEQ + srow) * DKH + d] = f2bf(acc[m][n][r] * scale);
                }
    } else {
        unsigned short* O = OutBase + 6291456;  // V^T [768][SEQ]
#pragma unroll
        for (int m = 0; m < 4; m++)
#pragma unroll
            for (int n = 0; n < 2; n++) {
                // key permute: swap bit2<->bit3 within each 16-key group so the
                // PV B-fragment (P) is a straight pack of consecutive S-regs.
                int srow0 = rowBase + wr * 64 + m * 16 + lg * 4;  // 4-aligned
                int pos0 = (srow0 & ~15) | ((srow0 & 4) << 1) | ((srow0 & 8) >> 1);
                int col = colBase + wc * 32 + n * 16 + lr;
                ushort4 o4;
                o4.x = f2bf(acc[m][n][0]);
                o4.y = f2bf(acc[m][n][1]);
                o4.z = f2bf(acc[m][n][2]);
                o4.w = f2bf(acc[m][n][3]);
                *(ushort4*)(O + (size_t)col * SEQ + pos0) = o4;
            }
    }
}

// ---------------------------------------------------------------- output GEMM
// A = AO [4096][768] bf16, B = wo [768][768] bf16, out f32 [4096][768].
__global__ __launch_bounds__(256, 2)
void gemm_o(const unsigned short* __restrict__ A,
            const unsigned short* __restrict__ B,
            float* __restrict__ Out) {
    __shared__ __align__(128) char smem[49152];

    const int t = threadIdx.x;
    const int wid = t >> 6, lane = t & 63;
    const int lr = lane & 15, lg = lane >> 4;
    const int wr = wid >> 1, wc = wid & 1;
    const int rowBase = blockIdx.x * 128;
    const int colBase = blockIdx.y * 64;

    const floatx4 zero4 = {0.f, 0.f, 0.f, 0.f};
    floatx4 acc[4][2];
#pragma unroll
    for (int m = 0; m < 4; m++)
#pragma unroll
        for (int n = 0; n < 2; n++) acc[m][n] = zero4;

    STAGE_G(0, 0);
    for (int i = 0; i < 12; ++i) {
        __builtin_amdgcn_s_barrier();
        __builtin_amdgcn_sched_barrier(0);
        if (i < 11) {
            STAGE_G((i + 1) & 1, (i + 1) * 64);
            asm volatile("s_waitcnt vmcnt(6)" ::: "memory");
        } else {
            asm volatile("s_waitcnt vmcnt(0)" ::: "memory");
        }
        __builtin_amdgcn_s_barrier();
        __builtin_amdgcn_sched_barrier(0);
        char* As = smem + (i & 1) * 24576;
        GEMM_COMPUTE(As, As + 16384);
    }

#pragma unroll
    for (int m = 0; m < 4; m++)
#pragma unroll
        for (int n = 0; n < 2; n++)
#pragma unroll
            for (int r = 0; r < 4; r++) {
                int srow = rowBase + wr * 64 + m * 16 + lg * 4 + r;
                int col = colBase + wc * 32 + n * 16 + lr;
                Out[(size_t)srow * DMODEL + col] = acc[m][n][r];
            }
}

// ---------------------------------------------------------------- flash attention
// Q,K: [H][SEQ][64] bf16 (Q pre-scaled by log2e/8). Vt: [768][SEQ] bf16 with
// bit2<->bit3 key permute per 16-key group. AO: [SEQ][768] bf16.
// 2 waves x 32 q-rows (128 threads). KVBLK=128, mfma 32x32x16 (2x MACs per
// LDS byte vs 16x16x32 -> LDS-read pipe, the R6 bottleneck, halves).
// LDS: K dbuf 2x16K + V 2x8K halves = 48KB, all 128B rows (R5: 0 conflicts).
#define STAGE_KA(bsel, kv0)                                                            \
    do {                                                                               \
        char* Kd_ = smem + (bsel) * 16384;                                             \
        _Pragma("unroll") for (int ii = 0; ii < 8; ii++) {                             \
            int o = ii * 2048 + t * 16;                                                \
            int row = o >> 7, colb = o & 127;                                          \
            async_copy16(Kd_ + ii * 2048 + wid * 1024,                                 \
                         (const char*)(Kp + headOff + (size_t)((kv0) + row) * DKH)     \
                             + swz(row, colb));                                        \
        }                                                                              \
    } while (0)

// V^T tile [64 feat][128 keys] as two [64][64] halves (128B rows each)
#define STAGE_VA(kv0)                                                                  \
    do {                                                                               \
        char* Vd_ = smem + 32768;                                                      \
        _Pragma("unroll") for (int hh = 0; hh < 2; hh++)                               \
            _Pragma("unroll") for (int ii = 0; ii < 4; ii++) {                         \
                int o = ii * 2048 + t * 16;                                            \
                int row = o >> 7, colb = o & 127;                                      \
                async_copy16(Vd_ + hh * 8192 + ii * 2048 + wid * 1024,                 \
                             (const char*)(Vt + (size_t)(h * DKH + row) * SEQ          \
                                           + (kv0) + hh * 64) + swz(row, colb));       \
            }                                                                          \
    } while (0)

__global__ __launch_bounds__(128, 2)
void attn_k(const unsigned short* __restrict__ Q,
            const unsigned short* __restrict__ Kp,
            const unsigned short* __restrict__ Vt,
            unsigned short* __restrict__ AO) {
    __shared__ __align__(128) char smem[49152];  // K0 16K | K1 16K | V 16K

    const int t = threadIdx.x;
    const int wid = t >> 6, lane = t & 63;
    const int q31 = lane & 31, hi = lane >> 5;

    // XCD-aware bijective swizzle: 768 blocks = 8 XCDs x 96
    int nid = (blockIdx.x & 7) * 96 + (blockIdx.x >> 3);
    const int h = nid >> 6, qb = nid & 63;
    const size_t headOff = (size_t)h * SEQ * DKH;

    // Q B-fragments (4 k-steps of 16 d): q = lane&31, d = ks*16 + hi*8 + j
    const unsigned short* qptr =
        Q + headOff + (size_t)(qb * 64 + wid * 32 + q31) * DKH + hi * 8;
    short8 qf[4];
#pragma unroll
    for (int ks = 0; ks < 4; ks++) qf[ks] = *(const short8*)(qptr + ks * 16);

    const floatx16 z16 = {0.f, 0.f, 0.f, 0.f, 0.f, 0.f, 0.f, 0.f,
                          0.f, 0.f, 0.f, 0.f, 0.f, 0.f, 0.f, 0.f};
    float mrun = -3.0e38f, lrun = 0.f;
    floatx16 accO[2] = {z16, z16};

    STAGE_KA(0, 0);

    for (int tt = 0; tt < 32; ++tt) {
        asm volatile("s_waitcnt vmcnt(0)" ::: "memory");  // own K(tt) retired
        __builtin_amdgcn_s_barrier();   // both waves: K(tt) visible; PV(tt-1) done
        __builtin_amdgcn_sched_barrier(0);
        STAGE_VA(tt * 128);                                   // 8 loads
        if (tt < 31) STAGE_KA((tt + 1) & 1, (tt + 1) * 128);  // 8 loads
        __builtin_amdgcn_sched_barrier(0);

        const char* Ks = smem + (tt & 1) * 16384;
        const char* Vs = smem + 32768;

        // S^T[key][q] = mfma32(K, Q): lane q = lane&31; keys per keyblock kb:
        // key = kb*32 + (r&3) + 8*(r>>2) + 4*hi
        floatx16 s[4] = {z16, z16, z16, z16};
        __builtin_amdgcn_s_setprio(1);
#pragma unroll
        for (int kb = 0; kb < 4; kb++)
#pragma unroll
            for (int ks = 0; ks < 4; ks++) {
                int row = kb * 32 + q31;
                int byteo = (row * 128 + ks * 32 + hi * 16) ^ ((q31 & 7) << 4);
                short8 kf = *(const short8*)(Ks + byteo);
                s[kb] = __builtin_amdgcn_mfma_f32_32x32x16_bf16(kf, qf[ks], s[kb], 0, 0, 0);
            }
        __builtin_amdgcn_s_setprio(0);

        // online softmax (exp2 domain); q's partner lane is lane^32
        float mk[4];
#pragma unroll
        for (int kb = 0; kb < 4; kb++) {
            float a = fmaxf(fmaxf(s[kb][0], s[kb][1]), fmaxf(s[kb][2], s[kb][3]));
            float b = fmaxf(fmaxf(s[kb][4], s[kb][5]), fmaxf(s[kb][6], s[kb][7]));
            float c = fmaxf(fmaxf(s[kb][8], s[kb][9]), fmaxf(s[kb][10], s[kb][11]));
            float d = fmaxf(fmaxf(s[kb][12], s[kb][13]), fmaxf(s[kb][14], s[kb][15]));
            mk[kb] = fmaxf(fmaxf(a, b), fmaxf(c, d));
        }
        float mt = fmaxf(fmaxf(mk[0], mk[1]), fmaxf(mk[2], mk[3]));
        mt = fmaxf(mt, __shfl_xor(mt, 32));
        if (!__all(mt <= mrun + 8.0f)) {        // defer-max (T13)
            float mnew = fmaxf(mrun, mt);
            float al = exp2fast(mrun - mnew);
#pragma unroll
            for (int fb = 0; fb < 2; fb++)
#pragma unroll
                for (int j = 0; j < 16; j++) accO[fb][j] *= al;
            lrun *= al;
            mrun = mnew;
        }
#pragma unroll
        for (int kb = 0; kb < 4; kb++)
#pragma unroll
            for (int j = 0; j < 16; j++) s[kb][j] = exp2fast(s[kb][j] - mrun);
        float sum = 0.f;
#pragma unroll
        for (int kb = 0; kb < 4; kb++) {
            float a = (s[kb][0] + s[kb][1]) + (s[kb][2] + s[kb][3]);
            float b = (s[kb][4] + s[kb][5]) + (s[kb][6] + s[kb][7]);
            float c = (s[kb][8] + s[kb][9]) + (s[kb][10] + s[kb][11]);
            float d = (s[kb][12] + s[kb][13]) + (s[kb][14] + s[kb][15]);
            sum += (a + b) + (c + d);
        }
        sum += __shfl_xor(sum, 32);
        lrun += sum;

        if (tt < 31) asm volatile("s_waitcnt vmcnt(8)" ::: "memory");  // V(tt) in, K(tt+1) flying
        else         asm volatile("s_waitcnt vmcnt(0)" ::: "memory");
        __builtin_amdgcn_s_barrier();   // both waves' V(tt) visible
        __builtin_amdgcn_sched_barrier(0);

        // PV: O^T[feat][q] += mfma32(V^T, P). V's key permute makes pf a
        // straight pack of consecutive S-regs (keys {0-3,8-11}+4hi per chunk).
        __builtin_amdgcn_s_setprio(1);
#pragma unroll
        for (int c = 0; c < 8; c++) {
            const int kb = c >> 1, r0 = (c & 1) * 8;
            uint4 pw;
            pw.x = cvt_pk_bf16(s[kb][r0 + 0], s[kb][r0 + 1]);
            pw.y = cvt_pk_bf16(s[kb][r0 + 2], s[kb][r0 + 3]);
            pw.z = cvt_pk_bf16(s[kb][r0 + 4], s[kb][r0 + 5]);
            pw.w = cvt_pk_bf16(s[kb][r0 + 6], s[kb][r0 + 7]);
            short8 pf = *(const short8*)&pw;
#pragma unroll
            for (int fb = 0; fb < 2; fb++) {
                int row = fb * 32 + q31;
                int byteo = ((c >> 2) * 8192 + row * 128 + (c & 3) * 32 + hi * 16)
                            ^ ((q31 & 7) << 4);
                short8 vf = *(const short8*)(Vs + byteo);
                accO[fb] = __builtin_amdgcn_mfma_f32_32x32x16_bf16(vf, pf, accO[fb], 0, 0, 0);
            }
        }
        __builtin_amdgcn_s_setprio(0);
    }

    // epilogue: accO[fb][r] = O^T[feat = fb*32 + (r&3)+8*(r>>2)+4*hi][q]
    float inv = 1.0f / lrun;
    int srow = qb * 64 + wid * 32 + q31;
#pragma unroll
    for (int fb = 0; fb < 2; fb++)
#pragma unroll
        for (int rq = 0; rq < 4; rq++) {
            ushort4 o4;
            o4.x = f2bf(accO[fb][4 * rq + 0] * inv);
            o4.y = f2bf(accO[fb][4 * rq + 1] * inv);
            o4.z = f2bf(accO[fb][4 * rq + 2] * inv);
            o4.w = f2bf(accO[fb][4 * rq + 3] * inv);
            int col = h * DKH + fb * 32 + rq * 8 + hi * 4;
            *(ushort4*)(AO + (size_t)srow * DMODEL + col) = o4;
        }
}

// ---------------------------------------------------------------- launch
extern "C" void kernel_launch(void* const* d_in, const int* in_sizes, int n_in,
                              void* d_out, int out_size, void* d_ws, size_t ws_size,
                              hipStream_t stream) {
    const float* x  = (const float*)d_in[0];
    const float* wq = (const float*)d_in[1];
    const float* wk = (const float*)d_in[2];
    const float* wv = (const float*)d_in[3];
    const float* wo = (const float*)d_in[4];

    char* ws = (char*)d_ws;
    unsigned short* xb  = (unsigned short*)(ws + 0);         // 4096x768 bf16
    unsigned short* wqb = (unsigned short*)(ws + 6291456);   // wq|wk|wv|wo contiguous
    unsigned short* wob = (unsigned short*)(ws + 9830400);
    unsigned short* Qb  = (unsigned short*)(ws + 11010048);  // Q|K|V^T contiguous
    unsigned short* Kb  = (unsigned short*)(ws + 17301504);
    unsigned short* VTb = (unsigned short*)(ws + 23592960);  // [768][4096] key-permuted
    unsigned short* AOb = (unsigned short*)(ws + 29884416);  // [4096][768]

    castk<<<3072, 256, 0, stream>>>(x, xb, 786432);
    castw<<<2304, 256, 0, stream>>>(wq, wk, wv, wo, wqb);

    // Q pre-scaled by log2(e)/sqrt(64) so softmax runs in exp2 domain
    gemm_qkv<<<dim3(32, 36), 256, 0, stream>>>(xb, wqb, Qb, 0.18033688f);

    attn_k<<<dim3(768), 128, 0, stream>>>(Qb, Kb, VTb, AOb);

    gemm_o<<<dim3(32, 12), 256, 0, stream>>>(AOb, wob, (float*)d_out);
}

// Round 8
// 119.342 us; speedup vs baseline: 1.1012x; 1.1012x over previous
//
#include <hip/hip_runtime.h>
#include <stdint.h>

#define SEQ 4096
#define DMODEL 768
#define NHEADS 12
#define DKH 64

typedef __attribute__((ext_vector_type(8))) short short8;
typedef __attribute__((ext_vector_type(4))) float floatx4;
typedef __attribute__((ext_vector_type(16))) float floatx16;

__device__ __forceinline__ unsigned short f2bf(float f) {
    unsigned int u = __float_as_uint(f);
    u += 0x7fffu + ((u >> 16) & 1u);          // round-to-nearest-even
    return (unsigned short)(u >> 16);
}

__device__ __forceinline__ float exp2fast(float x) {
    return __builtin_amdgcn_exp2f(x);
}

__device__ __forceinline__ unsigned int cvt_pk_bf16(float lo, float hi) {
    unsigned int r;
    asm("v_cvt_pk_bf16_f32 %0, %1, %2" : "=v"(r) : "v"(lo), "v"(hi));
    return r;
}

// XOR swizzle: spread a row-strided access across 8 16-byte slots.
__device__ __forceinline__ int swz(int row, int colb) {
    return colb ^ ((row & 7) << 4);
}

// async global->LDS, 16 bytes per lane. LDS dest wave-uniform base + lane*16.
__device__ __forceinline__ void async_copy16(void* lds, const void* g) {
    __builtin_amdgcn_global_load_lds(
        (const __attribute__((address_space(1))) void*)g,
        (__attribute__((address_space(3))) void*)lds,
        16, 0, 0);
}

// ---------------------------------------------------------------- casts
__global__ __launch_bounds__(256) void castk(const float* __restrict__ src,
                                             unsigned short* __restrict__ dst,
                                             int n4) {
    int i = blockIdx.x * 256 + threadIdx.x;
    if (i >= n4) return;
    float4 v = ((const float4*)src)[i];
    ushort4 o;
    o.x = f2bf(v.x); o.y = f2bf(v.y); o.z = f2bf(v.z); o.w = f2bf(v.w);
    ((ushort4*)dst)[i] = o;
}

// all four 768x768 weights in one launch; dst regions contiguous
__global__ __launch_bounds__(256) void castw(const float* __restrict__ w0,
                                             const float* __restrict__ w1,
                                             const float* __restrict__ w2,
                                             const float* __restrict__ w3,
                                             unsigned short* __restrict__ dst) {
    int b = blockIdx.x;              // 2304 = 4 * 576
    int wsel = b / 576;
    int i = (b % 576) * 256 + threadIdx.x;   // < 147456 float4 groups
    const float* src = (wsel == 0) ? w0 : (wsel == 1) ? w1 : (wsel == 2) ? w2 : w3;
    float4 v = ((const float4*)src)[i];
    ushort4 o;
    o.x = f2bf(v.x); o.y = f2bf(v.y); o.z = f2bf(v.z); o.w = f2bf(v.w);
    ((ushort4*)(dst + (size_t)wsel * 589824))[i] = o;
}

// stage one 128x64 A-tile + 64x64 B-tile into LDS buffer (6 loads/wave, 256 thr)
#define STAGE_G(bsel, kb)                                                              \
    do {                                                                               \
        char* As_ = smem + (bsel) * 24576;                                             \
        _Pragma("unroll") for (int ii = 0; ii < 4; ii++) {                             \
            int o = ii * 4096 + t * 16;                                                \
            int row = o >> 7, colb = o & 127;                                          \
            async_copy16(As_ + ii * 4096 + wid * 1024,                                 \
                         (const char*)A + ((size_t)(rowBase + row) * DMODEL + (kb)) * 2 \
                             + swz(row, colb));                                        \
        }                                                                              \
        _Pragma("unroll") for (int ii = 0; ii < 2; ii++) {                             \
            int o = ii * 4096 + t * 16;                                                \
            int row = o >> 7, colb = o & 127;                                          \
            async_copy16(As_ + 16384 + ii * 4096 + wid * 1024,                         \
                         (const char*)B + ((size_t)(colBase + row) * DMODEL + (kb)) * 2 \
                             + swz(row, colb));                                        \
        }                                                                              \
    } while (0)

// shared inner compute for the 128x64 GEMM tile (16 MFMA per wave)
#define GEMM_COMPUTE(As, Bs)                                                           \
    do {                                                                               \
        short8 a_[4][2], b_[2][2];                                                     \
        _Pragma("unroll") for (int m = 0; m < 4; m++)                                  \
            _Pragma("unroll") for (int kk = 0; kk < 2; kk++) {                         \
                int row = wr * 64 + m * 16 + lr;                                       \
                int colb = kk * 64 + lg * 16;                                          \
                a_[m][kk] = *(const short8*)((As) + row * 128 + swz(row, colb));       \
            }                                                                          \
        _Pragma("unroll") for (int n = 0; n < 2; n++)                                  \
            _Pragma("unroll") for (int kk = 0; kk < 2; kk++) {                         \
                int row = wc * 32 + n * 16 + lr;                                       \
                int colb = kk * 64 + lg * 16;                                          \
                b_[n][kk] = *(const short8*)((Bs) + row * 128 + swz(row, colb));       \
            }                                                                          \
        _Pragma("unroll") for (int m = 0; m < 4; m++)                                  \
            _Pragma("unroll") for (int n = 0; n < 2; n++)                              \
                _Pragma("unroll") for (int kk = 0; kk < 2; kk++)                       \
                    acc[m][n] = __builtin_amdgcn_mfma_f32_16x16x32_bf16(               \
                        a_[m][kk], b_[n][kk], acc[m][n], 0, 0, 0);                     \
    } while (0)

// ---------------------------------------------------------------- fused QKV GEMM
// A [4096][768] bf16; W = wq|wk|wv contiguous ([out][in] each).
// grid (32, 36): by/12 = proj (0:Q scaled, 1:K, 2:V^T), by%12 = col tile.
// Out: Qb | Kb ([H][SEQ][64]) | VTb ([768][SEQ], bit2<->bit3 key permute).
__global__ __launch_bounds__(256, 2)
void gemm_qkv(const unsigned short* __restrict__ A,
              const unsigned short* __restrict__ W,
              unsigned short* __restrict__ OutBase, float qscale) {
    __shared__ __align__(128) char smem[49152];  // 2 x (A 16K | B 8K)

    const int t = threadIdx.x;
    const int wid = t >> 6, lane = t & 63;
    const int lr = lane & 15, lg = lane >> 4;
    const int wr = wid >> 1, wc = wid & 1;
    const int rowBase = blockIdx.x * 128;
    const int proj = blockIdx.y / 12;
    const int colBase = (blockIdx.y % 12) * 64;
    const unsigned short* B = W + (size_t)proj * 589824;

    const floatx4 zero4 = {0.f, 0.f, 0.f, 0.f};
    floatx4 acc[4][2];
#pragma unroll
    for (int m = 0; m < 4; m++)
#pragma unroll
        for (int n = 0; n < 2; n++) acc[m][n] = zero4;

    STAGE_G(0, 0);
    for (int i = 0; i < 12; ++i) {
        __builtin_amdgcn_s_barrier();              // all waves done reading buf[(i+1)&1]
        __builtin_amdgcn_sched_barrier(0);
        if (i < 11) {
            STAGE_G((i + 1) & 1, (i + 1) * 64);
            asm volatile("s_waitcnt vmcnt(6)" ::: "memory");  // own stage(i) done
        } else {
            asm volatile("s_waitcnt vmcnt(0)" ::: "memory");
        }
        __builtin_amdgcn_s_barrier();              // everyone's stage(i) done
        __builtin_amdgcn_sched_barrier(0);
        char* As = smem + (i & 1) * 24576;
        GEMM_COMPUTE(As, As + 16384);
    }

    if (proj < 2) {
        unsigned short* O = OutBase + (size_t)proj * 3145728;
        float scale = (proj == 0) ? qscale : 1.0f;
#pragma unroll
        for (int m = 0; m < 4; m++)
#pragma unroll
            for (int n = 0; n < 2; n++)
#pragma unroll
                for (int r = 0; r < 4; r++) {
                    int srow = rowBase + wr * 64 + m * 16 + lg * 4 + r;
                    int col = colBase + wc * 32 + n * 16 + lr;
                    int h = col >> 6, d = col & 63;
                    O[((size_t)h * SEQ + srow) * DKH + d] = f2bf(acc[m][n][r] * scale);
                }
    } else {
        unsigned short* O = OutBase + 6291456;  // V^T [768][SEQ]
#pragma unroll
        for (int m = 0; m < 4; m++)
#pragma unroll
            for (int n = 0; n < 2; n++) {
                // key permute: swap bit2<->bit3 within each 16-key group so the
                // PV B-fragment (P) is a straight pack of consecutive S-regs.
                int srow0 = rowBase + wr * 64 + m * 16 + lg * 4;  // 4-aligned
                int pos0 = (srow0 & ~15) | ((srow0 & 4) << 1) | ((srow0 & 8) >> 1);
                int col = colBase + wc * 32 + n * 16 + lr;
                ushort4 o4;
                o4.x = f2bf(acc[m][n][0]);
                o4.y = f2bf(acc[m][n][1]);
                o4.z = f2bf(acc[m][n][2]);
                o4.w = f2bf(acc[m][n][3]);
                *(ushort4*)(O + (size_t)col * SEQ + pos0) = o4;
            }
    }
}

// ---------------------------------------------------------------- output GEMM
// A = AO [4096][768] bf16, B = wo [768][768] bf16, out f32 [4096][768].
__global__ __launch_bounds__(256, 2)
void gemm_o(const unsigned short* __restrict__ A,
            const unsigned short* __restrict__ B,
            float* __restrict__ Out) {
    __shared__ __align__(128) char smem[49152];

    const int t = threadIdx.x;
    const int wid = t >> 6, lane = t & 63;
    const int lr = lane & 15, lg = lane >> 4;
    const int wr = wid >> 1, wc = wid & 1;
    const int rowBase = blockIdx.x * 128;
    const int colBase = blockIdx.y * 64;

    const floatx4 zero4 = {0.f, 0.f, 0.f, 0.f};
    floatx4 acc[4][2];
#pragma unroll
    for (int m = 0; m < 4; m++)
#pragma unroll
        for (int n = 0; n < 2; n++) acc[m][n] = zero4;

    STAGE_G(0, 0);
    for (int i = 0; i < 12; ++i) {
        __builtin_amdgcn_s_barrier();
        __builtin_amdgcn_sched_barrier(0);
        if (i < 11) {
            STAGE_G((i + 1) & 1, (i + 1) * 64);
            asm volatile("s_waitcnt vmcnt(6)" ::: "memory");
        } else {
            asm volatile("s_waitcnt vmcnt(0)" ::: "memory");
        }
        __builtin_amdgcn_s_barrier();
        __builtin_amdgcn_sched_barrier(0);
        char* As = smem + (i & 1) * 24576;
        GEMM_COMPUTE(As, As + 16384);
    }

#pragma unroll
    for (int m = 0; m < 4; m++)
#pragma unroll
        for (int n = 0; n < 2; n++)
#pragma unroll
            for (int r = 0; r < 4; r++) {
                int srow = rowBase + wr * 64 + m * 16 + lg * 4 + r;
                int col = colBase + wc * 32 + n * 16 + lr;
                Out[(size_t)srow * DMODEL + col] = acc[m][n][r];
            }
}

// ---------------------------------------------------------------- flash attention
// Q,K: [H][SEQ][64] bf16 (Q pre-scaled by log2e/8). Vt: [768][SEQ] bf16 with
// bit2<->bit3 key permute per 16-key group. AO: [SEQ][768] bf16.
// 4 waves: wave = (q-group g = wid>>1 [32 q-rows], key-half e = wid&1 [64 keys]).
// Independent online softmax per wave over its key half; flash-merge of the
// (m, l, O) pairs once at the end through LDS. KVBLK=128, mfma 32x32x16.
// LDS tiles stored CHUNK-REORDERED so every ds_read_b128 instruction reads one
// contiguous 1KB block (lane slot = q31*2+hi) -> stride-1, bank-conflict-free.
// K chunk addr:  ((kb2*4+ks)*64 + q31*2 + hi)*16   (kb2 = e*2+kb)
// V chunk addr:  (((e*4+c)*2+fb)*64 + q31*2 + hi)*16
// The permutation is folded into the global_load_lds SOURCE (dest stays linear).
#define STAGE_K8(bsel, kv0)                                                            \
    do {                                                                               \
        char* Kd_ = smem + (bsel) * 16384;                                             \
        _Pragma("unroll") for (int ii = 0; ii < 4; ii++) {                             \
            int cc = ii * 256 + wid * 64 + lane;                                       \
            int gk = cc >> 6, qd = (cc >> 1) & 31, hh = cc & 1;                        \
            int kb2 = gk >> 2, ks2 = gk & 3;                                           \
            int key = kb2 * 32 + qd;                                                   \
            async_copy16(Kd_ + (ii * 256 + wid * 64) * 16,                             \
                         (const char*)(Kp + headOff) + (size_t)((kv0) + key) * 128     \
                             + (ks2 * 2 + hh) * 16);                                   \
        }                                                                              \
    } while (0)

#define STAGE_V8(kv0)                                                                  \
    do {                                                                               \
        char* Vd_ = smem + 32768;                                                      \
        _Pragma("unroll") for (int ii = 0; ii < 4; ii++) {                             \
            int cc = ii * 256 + wid * 64 + lane;                                       \
            int gv = cc >> 6, qd = (cc >> 1) & 31, hh = cc & 1;                        \
            int fbv = gv & 1, cv = (gv >> 1) & 3, ev = gv >> 3;                        \
            int feat = fbv * 32 + qd;                                                  \
            int p0 = ev * 64 + cv * 16 + hh * 8;                                       \
            async_copy16(Vd_ + (ii * 256 + wid * 64) * 16,                             \
                         (const char*)Vt                                               \
                             + ((size_t)(h * DKH + feat) * SEQ + (kv0) + p0) * 2);     \
        }                                                                              \
    } while (0)

__global__ __launch_bounds__(256, 3)
void attn_k(const unsigned short* __restrict__ Q,
            const unsigned short* __restrict__ Kp,
            const unsigned short* __restrict__ Vt,
            unsigned short* __restrict__ AO) {
    __shared__ __align__(128) char smem[49152];  // K0 16K | K1 16K | V 16K

    const int t = threadIdx.x;
    const int wid = t >> 6, lane = t & 63;
    const int q31 = lane & 31, hi = lane >> 5;
    const int g = wid >> 1, e = wid & 1;

    // XCD-aware bijective swizzle: 768 blocks = 8 XCDs x 96
    int nid = (blockIdx.x & 7) * 96 + (blockIdx.x >> 3);
    const int h = nid >> 6, qb = nid & 63;
    const size_t headOff = (size_t)h * SEQ * DKH;

    // Q B-fragments (4 k-steps of 16 d): q-row = qb*64 + g*32 + q31, d = ks*16+hi*8+j
    const unsigned short* qptr =
        Q + headOff + (size_t)(qb * 64 + g * 32 + q31) * DKH + hi * 8;
    short8 qf[4];
#pragma unroll
    for (int ks = 0; ks < 4; ks++) qf[ks] = *(const short8*)(qptr + ks * 16);

    const floatx16 z16 = {0.f, 0.f, 0.f, 0.f, 0.f, 0.f, 0.f, 0.f,
                          0.f, 0.f, 0.f, 0.f, 0.f, 0.f, 0.f, 0.f};
    float mrun = -3.0e38f, lrun = 0.f;
    floatx16 accO[2] = {z16, z16};

    STAGE_K8(0, 0);

    for (int tt = 0; tt < 32; ++tt) {
        asm volatile("s_waitcnt vmcnt(0)" ::: "memory");  // own K(tt) retired
        __builtin_amdgcn_s_barrier();   // all waves: K(tt) visible; PV(tt-1) done
        __builtin_amdgcn_sched_barrier(0);
        STAGE_V8(tt * 128);                                   // 4 issues
        if (tt < 31) STAGE_K8((tt + 1) & 1, (tt + 1) * 128);  // 4 issues
        __builtin_amdgcn_sched_barrier(0);

        const char* Ks = smem + (tt & 1) * 16384;
        const char* Vs = smem + 32768;

        // S^T[key][q] over this wave's 64-key half: 2 keyblocks x 4 k-steps
        floatx16 s[2] = {z16, z16};
        __builtin_amdgcn_s_setprio(1);
#pragma unroll
        for (int kb = 0; kb < 2; kb++) {
            const int kb2 = e * 2 + kb;
#pragma unroll
            for (int ks = 0; ks < 4; ks++) {
                short8 kf = *(const short8*)(
                    Ks + ((kb2 * 4 + ks) * 64 + q31 * 2 + hi) * 16);
                s[kb] = __builtin_amdgcn_mfma_f32_32x32x16_bf16(kf, qf[ks], s[kb], 0, 0, 0);
            }
        }
        __builtin_amdgcn_s_setprio(0);

        // online softmax over this wave's 32 S-values (exp2 domain)
        float mk[2];
#pragma unroll
        for (int kb = 0; kb < 2; kb++) {
            float a = fmaxf(fmaxf(s[kb][0], s[kb][1]), fmaxf(s[kb][2], s[kb][3]));
            float b = fmaxf(fmaxf(s[kb][4], s[kb][5]), fmaxf(s[kb][6], s[kb][7]));
            float c = fmaxf(fmaxf(s[kb][8], s[kb][9]), fmaxf(s[kb][10], s[kb][11]));
            float d = fmaxf(fmaxf(s[kb][12], s[kb][13]), fmaxf(s[kb][14], s[kb][15]));
            mk[kb] = fmaxf(fmaxf(a, b), fmaxf(c, d));
        }
        float mt = fmaxf(mk[0], mk[1]);
        mt = fmaxf(mt, __shfl_xor(mt, 32));
        if (!__all(mt <= mrun + 8.0f)) {        // defer-max (T13)
            float mnew = fmaxf(mrun, mt);
            float al = exp2fast(mrun - mnew);
#pragma unroll
            for (int fb = 0; fb < 2; fb++)
#pragma unroll
                for (int j = 0; j < 16; j++) accO[fb][j] *= al;
            lrun *= al;
            mrun = mnew;
        }
#pragma unroll
        for (int kb = 0; kb < 2; kb++)
#pragma unroll
            for (int j = 0; j < 16; j++) s[kb][j] = exp2fast(s[kb][j] - mrun);
        float sum = 0.f;
#pragma unroll
        for (int kb = 0; kb < 2; kb++) {
            float a = (s[kb][0] + s[kb][1]) + (s[kb][2] + s[kb][3]);
            float b = (s[kb][4] + s[kb][5]) + (s[kb][6] + s[kb][7]);
            float c = (s[kb][8] + s[kb][9]) + (s[kb][10] + s[kb][11]);
            float d = (s[kb][12] + s[kb][13]) + (s[kb][14] + s[kb][15]);
            sum += (a + b) + (c + d);
        }
        sum += __shfl_xor(sum, 32);
        lrun += sum;

        if (tt < 31) asm volatile("s_waitcnt vmcnt(4)" ::: "memory");  // V(tt) in, K flying
        else         asm volatile("s_waitcnt vmcnt(0)" ::: "memory");
        __builtin_amdgcn_s_barrier();   // all waves' V(tt) visible
        __builtin_amdgcn_sched_barrier(0);

        // PV over this wave's key half: 4 k-steps x 2 feature blocks
        __builtin_amdgcn_s_setprio(1);
#pragma unroll
        for (int c = 0; c < 4; c++) {
            const int kb = c >> 1, r0 = (c & 1) * 8;
            uint4 pw;
            pw.x = cvt_pk_bf16(s[kb][r0 + 0], s[kb][r0 + 1]);
            pw.y = cvt_pk_bf16(s[kb][r0 + 2], s[kb][r0 + 3]);
            pw.z = cvt_pk_bf16(s[kb][r0 + 4], s[kb][r0 + 5]);
            pw.w = cvt_pk_bf16(s[kb][r0 + 6], s[kb][r0 + 7]);
            short8 pf = *(const short8*)&pw;
#pragma unroll
            for (int fb = 0; fb < 2; fb++) {
                short8 vf = *(const short8*)(
                    Vs + (((e * 4 + c) * 2 + fb) * 64 + q31 * 2 + hi) * 16);
                accO[fb] = __builtin_amdgcn_mfma_f32_32x32x16_bf16(vf, pf, accO[fb], 0, 0, 0);
            }
        }
        __builtin_amdgcn_s_setprio(0);
    }

    // ---- flash-merge the two key-half waves of each q-group through LDS ----
    __builtin_amdgcn_s_barrier();       // everyone done reading K/V tiles
    char* R = smem + g * 9216 + lane * 144;
    if (e == 1) {
#pragma unroll
        for (int fb = 0; fb < 2; fb++)
#pragma unroll
            for (int j4 = 0; j4 < 4; j4++) {
                floatx4 v4 = {accO[fb][j4 * 4 + 0], accO[fb][j4 * 4 + 1],
                              accO[fb][j4 * 4 + 2], accO[fb][j4 * 4 + 3]};
                *(floatx4*)(R + fb * 64 + j4 * 16) = v4;
            }
        *(float*)(R + 128) = mrun;
        *(float*)(R + 132) = lrun;
        asm volatile("s_waitcnt lgkmcnt(0)" ::: "memory");
    }
    __builtin_amdgcn_s_barrier();
    __builtin_amdgcn_sched_barrier(0);
    if (e == 0) {
        float m1 = *(const float*)(R + 128);
        float l1 = *(const float*)(R + 132);
        float m = fmaxf(mrun, m1);
        float a0 = exp2fast(mrun - m), a1 = exp2fast(m1 - m);
        float inv = 1.0f / (lrun * a0 + l1 * a1);
        int srow = qb * 64 + g * 32 + q31;
#pragma unroll
        for (int fb = 0; fb < 2; fb++)
#pragma unroll
            for (int rq = 0; rq < 4; rq++) {
                floatx4 p4 = *(const floatx4*)(R + fb * 64 + rq * 16);
                ushort4 o4;
                o4.x = f2bf((accO[fb][4 * rq + 0] * a0 + p4[0] * a1) * inv);
                o4.y = f2bf((accO[fb][4 * rq + 1] * a0 + p4[1] * a1) * inv);
                o4.z = f2bf((accO[fb][4 * rq + 2] * a0 + p4[2] * a1) * inv);
                o4.w = f2bf((accO[fb][4 * rq + 3] * a0 + p4[3] * a1) * inv);
                int col = h * DKH + fb * 32 + rq * 8 + hi * 4;
                *(ushort4*)(AO + (size_t)srow * DMODEL + col) = o4;
            }
    }
}

// ---------------------------------------------------------------- launch
extern "C" void kernel_launch(void* const* d_in, const int* in_sizes, int n_in,
                              void* d_out, int out_size, void* d_ws, size_t ws_size,
                              hipStream_t stream) {
    const float* x  = (const float*)d_in[0];
    const float* wq = (const float*)d_in[1];
    const float* wk = (const float*)d_in[2];
    const float* wv = (const float*)d_in[3];
    const float* wo = (const float*)d_in[4];

    char* ws = (char*)d_ws;
    unsigned short* xb  = (unsigned short*)(ws + 0);         // 4096x768 bf16
    unsigned short* wqb = (unsigned short*)(ws + 6291456);   // wq|wk|wv|wo contiguous
    unsigned short* wob = (unsigned short*)(ws + 9830400);
    unsigned short* Qb  = (unsigned short*)(ws + 11010048);  // Q|K|V^T contiguous
    unsigned short* Kb  = (unsigned short*)(ws + 17301504);
    unsigned short* VTb = (unsigned short*)(ws + 23592960);  // [768][4096] key-permuted
    unsigned short* AOb = (unsigned short*)(ws + 29884416);  // [4096][768]

    castk<<<3072, 256, 0, stream>>>(x, xb, 786432);
    castw<<<2304, 256, 0, stream>>>(wq, wk, wv, wo, wqb);

    // Q pre-scaled by log2(e)/sqrt(64) so softmax runs in exp2 domain
    gemm_qkv<<<dim3(32, 36), 256, 0, stream>>>(xb, wqb, Qb, 0.18033688f);

    attn_k<<<dim3(768), 256, 0, stream>>>(Qb, Kb, VTb, AOb);

    gemm_o<<<dim3(32, 12), 256, 0, stream>>>(AOb, wob, (float*)d_out);
}